// Round 8
// baseline (102.109 us; speedup 1.0000x reference)
//
#include <hip/hip_runtime.h>

#define IN_CH 16
#define OUT_CH 32
#define NUM_INPUTS 144   // IN_CH * 3 * 3
#define H_ 32
#define W_ 32
#define TILE_H 4
#define LDS_H 6          // TILE_H + 2 halo
#define LDS_W 34
#define CHW (LDS_H * LDS_W)   // 204

typedef __attribute__((ext_vector_type(2))) float f32x2;

// ---------------------------------------------------------------------------
// R8: broadcast-read reduction. Grid (64 spatial, 8 quads) = 512 blocks =
// 2/CU (R6 lesson: never 1/CU); block 128 = 2 waves -> 4 waves/CU.
// Thread = 4 rows x 2 ch x 8 input chans. vs R7 this halves total waves ->
// halves wave-uniform table reads (the dominant LDS-pipe term, 11.5K->5.8K
// cyc/CU) and improves patch-read sharing (6 reads serve 4 rows).
//
// Layout: wave id = channel-pair pgrp (wave-uniform table base);
// in-wave half = input-channel split cs (lanes 0-31 cs0, 32-63 cs1).
// Dual-address table reads are bank-disjoint via a 1-slot stagger between
// cs halves (73-slot stride = 292 words = 4 mod 32 -> b128 bank groups
// {k..k+3} vs {k+4..k+7}). Patch reads: each half is 32-lane stride-1
// (1 addr/bank), halves' bases differ -> 2 addr/bank = free baseline (m136).
// cs-combine: __shfl_xor(.,32) in registers -> no atomics, no memset.
//
// Math per (i,o): y(p) = m0*p + b0 + (m1-m0)*max(p-p1,0)  (continuous at p1
// -> exactly reproduces the clipped-tail reference); per-tap b0 hoisted as a
// once-per-wave butterfly sum.
// ---------------------------------------------------------------------------
__global__ __launch_bounds__(128) void apc_fused(
        const float* __restrict__ x,
        const float* __restrict__ pos,
        const float* __restrict__ val,
        float* __restrict__ out) {
    __shared__ float  lx[IN_CH * CHW];   // 13056 B
    __shared__ float4 ltPM[2 * 146];     //  4672 B  [pgrp][cs*73 + t], slot 72 unused
    __shared__ f32x2  ltD [2 * 146];     //  2336 B
    __shared__ f32x2  ltB [2 * 146];     //  2336 B   (total 22.4 KB)

    int bx  = blockIdx.x;            // 0..63: b*8 + row_tile
    int b   = bx >> 3;
    int ho0 = (bx & 7) * TILE_H;
    int g   = blockIdx.y;            // channel-quad: o = 4g..4g+3
    int tid = threadIdx.x;

    // ---- Phase 0a: stage x tile (16ch x 6x34) with zero-padded halo. ------
    for (int idx = tid; idx < IN_CH * CHW; idx += 128) {
        int c   = idx / CHW;
        int rem = idx - c * CHW;
        int r   = rem / LDS_W;
        int col = rem - r * LDS_W;
        int gr  = ho0 + r - 1;
        int gc  = col - 1;
        float v = 0.f;
        if ((unsigned)gr < (unsigned)H_ && (unsigned)gc < (unsigned)W_)
            v = x[((b * IN_CH + c) * H_ + gr) * W_ + gc];
        lx[idx] = v;
    }

    // ---- Phase 0b: build table slice (144 taps over 128 threads). ---------
    for (int i = tid; i < NUM_INPUTS; i += 128) {
        // pos/val[(i,o,p)]: 4-ch slice = 12 floats at i*96 + g*12 (16B-align)
        const float4* pp = (const float4*)(pos + i * 96 + g * 12);
        const float4* vv = (const float4*)(val + i * 96 + g * 12);
        float4 pA = pp[0], pB = pp[1], pC = pp[2];
        float4 vA = vv[0], vB = vv[1], vC = vv[2];
        float P[12] = {pA.x,pA.y,pA.z,pA.w, pB.x,pB.y,pB.z,pB.w, pC.x,pC.y,pC.z,pC.w};
        float V[12] = {vA.x,vA.y,vA.z,vA.w, vB.x,vB.y,vB.z,vB.w, vC.x,vC.y,vC.z,vC.w};
        float p1[4], m0[4], dm[4], b0[4];
        #pragma unroll
        for (int k = 0; k < 4; ++k) {
            float q0 = P[3*k], q1 = P[3*k+1], q2 = P[3*k+2];
            float w0 = V[3*k], w1 = V[3*k+1], w2 = V[3*k+2];
            float s0 = (w1 - w0) / (q1 - q0);
            float s1 = (w2 - w1) / (q2 - q1);
            p1[k] = q1; m0[k] = s0; dm[k] = s1 - s0; b0[k] = w0 - s0 * q0;
        }
        int slot = (i < 72) ? i : (i + 1);   // cs-half stagger (bank shift 4)
        ltPM[slot]       = make_float4(p1[0], p1[1], m0[0], m0[1]);
        ltD [slot]       = (f32x2){dm[0], dm[1]};
        ltB [slot]       = (f32x2){b0[0], b0[1]};
        ltPM[146 + slot] = make_float4(p1[2], p1[3], m0[2], m0[3]);
        ltD [146 + slot] = (f32x2){dm[2], dm[3]};
        ltB [146 + slot] = (f32x2){b0[2], b0[3]};
    }
    __syncthreads();

    int col  = tid & 31;             // output col
    int cs   = (tid >> 5) & 1;       // input-channel half (in-wave)
    int pgrp = tid >> 6;             // channel pair (wave id, uniform)
    int hl   = tid & 31;             // half-lane id
    int tb0  = pgrp * 146 + cs * 73; // this half's table base
    int c0   = cs * 8;

    // bb = sum of b0 over this half's 72 taps (per-32-lane butterfly).
    f32x2 bb = ltB[tb0 + hl];
    bb += ltB[tb0 + 32 + hl];
    if (hl < 8) bb += ltB[tb0 + 64 + hl];
    #pragma unroll
    for (int m = 1; m < 32; m <<= 1) {
        bb.x += __shfl_xor(bb.x, m);
        bb.y += __shfl_xor(bb.y, m);
    }

    f32x2 a[4] = {{0,0},{0,0},{0,0},{0,0}};
    f32x2 h[4] = {{0,0},{0,0},{0,0},{0,0}};
    const f32x2 zz = {0.f, 0.f};

    #pragma unroll
    for (int cc = 0; cc < 8; ++cc) {
        int c = c0 + cc;
        #pragma unroll
        for (int kw = 0; kw < 3; ++kw) {
            // 6 shared input rows cover all 4 output rows' 3-tap kh windows.
            float pa[6];
            #pragma unroll
            for (int r = 0; r < 6; ++r)
                pa[r] = lx[c * CHW + r * LDS_W + col + kw];
            #pragma unroll
            for (int kh = 0; kh < 3; ++kh) {
                int t = (cc * 3 + kh) * 3 + kw;      // local tap 0..71
                float4 q = ltPM[tb0 + t];            // dual-addr b128, bank-disjoint
                f32x2  D = ltD [tb0 + t];
                f32x2  P = {q.x, q.y}, M = {q.z, q.w};
                #pragma unroll
                for (int r = 0; r < 4; ++r) {
                    f32x2 pv = {pa[r + kh], pa[r + kh]};
                    a[r] = __builtin_elementwise_fma(M, pv, a[r]);
                    h[r] = __builtin_elementwise_fma(
                        D, __builtin_elementwise_max(pv - P, zz), h[r]);
                }
            }
        }
    }

    // ---- Epilogue: cs-combine via shfl across half-waves, lanes<32 store. -
    int o0 = 4 * g + 2 * pgrp;
    int HW = H_ * W_;
    #pragma unroll
    for (int r = 0; r < 4; ++r) {
        f32x2 s = a[r] + h[r] + bb;              // bb halves sum to full SumB0
        s.x += __shfl_xor(s.x, 32);
        s.y += __shfl_xor(s.y, 32);
        if (cs == 0) {
            int ob = ((b * OUT_CH + o0) * H_ + (ho0 + r)) * W_ + col;
            out[ob     ] = s.x;
            out[ob + HW] = s.y;
        }
    }
}

extern "C" void kernel_launch(void* const* d_in, const int* in_sizes, int n_in,
                              void* d_out, int out_size, void* d_ws, size_t ws_size,
                              hipStream_t stream) {
    const float* x   = (const float*)d_in[0];
    const float* pos = (const float*)d_in[1];
    const float* val = (const float*)d_in[2];

    dim3 grid(64, 8);
    apc_fused<<<grid, 128, 0, stream>>>(x, pos, val, (float*)d_out);
}

// Round 9
// 74.476 us; speedup vs baseline: 1.3710x; 1.3710x over previous
//
#include <hip/hip_runtime.h>

#define IN_CH 16
#define OUT_CH 32
#define NUM_INPUTS 144   // IN_CH * 3 * 3
#define H_ 32
#define W_ 32
#define TILE_H 4
#define LDS_H 6          // TILE_H + 2 halo
#define LDS_W 34
#define CHW (LDS_H * LDS_W)   // 204

typedef __attribute__((ext_vector_type(2))) float f32x2;

// ---------------------------------------------------------------------------
// R9 = R8 with the register spill fixed. R8's fully-unrolled 72-tap body hit
// VGPR=256 + ~80MB scratch traffic (FETCH 37MB/WRITE 41MB) -> 63-75us.
// Fix: __launch_bounds__(128,2) caps VGPR at 128; cc-loop unrolled only 2x
// (inner kw/kh/row still fully unrolled). Live set ~60-70 VGPR -> no spill.
//
// Structure: grid (64 spatial, 8 quads) = 512 blocks = 2/CU; block 128 = 2
// waves. Thread = 4 rows x 2 ch x 8 input chans. Wave id = channel pair
// (wave-uniform table base); in-wave half = input-channel split cs.
// Table reads dual-addr bank-disjoint via 73-slot cs stagger; patch reads
// 2 addr/bank (free). cs-combine via __shfl_xor(.,32): no atomics/memset.
//
// Math per (i,o): y(p) = m0*p + b0 + (m1-m0)*max(p-p1,0)  (continuous at p1
// -> exactly reproduces the clipped-tail reference); per-tap b0 hoisted as a
// once-per-wave butterfly sum.
// ---------------------------------------------------------------------------
__global__ __launch_bounds__(128, 2) void apc_fused(
        const float* __restrict__ x,
        const float* __restrict__ pos,
        const float* __restrict__ val,
        float* __restrict__ out) {
    __shared__ float  lx[IN_CH * CHW];   // 13056 B
    __shared__ float4 ltPM[2 * 146];     //  4672 B  [pgrp][cs*73 + t], slot 72 unused
    __shared__ f32x2  ltD [2 * 146];     //  2336 B
    __shared__ f32x2  ltB [2 * 146];     //  2336 B   (total 22.4 KB)

    int bx  = blockIdx.x;            // 0..63: b*8 + row_tile
    int b   = bx >> 3;
    int ho0 = (bx & 7) * TILE_H;
    int g   = blockIdx.y;            // channel-quad: o = 4g..4g+3
    int tid = threadIdx.x;

    // ---- Phase 0a: stage x tile (16ch x 6x34) with zero-padded halo. ------
    for (int idx = tid; idx < IN_CH * CHW; idx += 128) {
        int c   = idx / CHW;
        int rem = idx - c * CHW;
        int r   = rem / LDS_W;
        int col = rem - r * LDS_W;
        int gr  = ho0 + r - 1;
        int gc  = col - 1;
        float v = 0.f;
        if ((unsigned)gr < (unsigned)H_ && (unsigned)gc < (unsigned)W_)
            v = x[((b * IN_CH + c) * H_ + gr) * W_ + gc];
        lx[idx] = v;
    }

    // ---- Phase 0b: build table slice (144 taps over 128 threads). ---------
    for (int i = tid; i < NUM_INPUTS; i += 128) {
        // pos/val[(i,o,p)]: 4-ch slice = 12 floats at i*96 + g*12 (16B-align)
        const float4* pp = (const float4*)(pos + i * 96 + g * 12);
        const float4* vv = (const float4*)(val + i * 96 + g * 12);
        float4 pA = pp[0], pB = pp[1], pC = pp[2];
        float4 vA = vv[0], vB = vv[1], vC = vv[2];
        float P[12] = {pA.x,pA.y,pA.z,pA.w, pB.x,pB.y,pB.z,pB.w, pC.x,pC.y,pC.z,pC.w};
        float V[12] = {vA.x,vA.y,vA.z,vA.w, vB.x,vB.y,vB.z,vB.w, vC.x,vC.y,vC.z,vC.w};
        float p1[4], m0[4], dm[4], b0[4];
        #pragma unroll
        for (int k = 0; k < 4; ++k) {
            float q0 = P[3*k], q1 = P[3*k+1], q2 = P[3*k+2];
            float w0 = V[3*k], w1 = V[3*k+1], w2 = V[3*k+2];
            float s0 = (w1 - w0) / (q1 - q0);
            float s1 = (w2 - w1) / (q2 - q1);
            p1[k] = q1; m0[k] = s0; dm[k] = s1 - s0; b0[k] = w0 - s0 * q0;
        }
        int slot = (i < 72) ? i : (i + 1);   // cs-half stagger (bank shift 4)
        ltPM[slot]       = make_float4(p1[0], p1[1], m0[0], m0[1]);
        ltD [slot]       = (f32x2){dm[0], dm[1]};
        ltB [slot]       = (f32x2){b0[0], b0[1]};
        ltPM[146 + slot] = make_float4(p1[2], p1[3], m0[2], m0[3]);
        ltD [146 + slot] = (f32x2){dm[2], dm[3]};
        ltB [146 + slot] = (f32x2){b0[2], b0[3]};
    }
    __syncthreads();

    int col  = tid & 31;             // output col
    int cs   = (tid >> 5) & 1;       // input-channel half (in-wave)
    int pgrp = tid >> 6;             // channel pair (wave id, uniform)
    int hl   = tid & 31;             // half-lane id
    int tb0  = pgrp * 146 + cs * 73; // this half's table base
    int c0   = cs * 8;

    // bb = sum of b0 over this half's 72 taps (per-32-lane butterfly).
    f32x2 bb = ltB[tb0 + hl];
    bb += ltB[tb0 + 32 + hl];
    if (hl < 8) bb += ltB[tb0 + 64 + hl];
    #pragma unroll
    for (int m = 1; m < 32; m <<= 1) {
        bb.x += __shfl_xor(bb.x, m);
        bb.y += __shfl_xor(bb.y, m);
    }

    f32x2 a[4] = {{0,0},{0,0},{0,0},{0,0}};
    f32x2 h[4] = {{0,0},{0,0},{0,0},{0,0}};
    const f32x2 zz = {0.f, 0.f};

    // Partial unroll (2x) keeps the live set ~60-70 VGPR: no spill at the
    // 128-VGPR cap, while inner kw/kh/row unrolls preserve ILP.
    #pragma unroll 2
    for (int cc = 0; cc < 8; ++cc) {
        int c = c0 + cc;
        #pragma unroll
        for (int kw = 0; kw < 3; ++kw) {
            // 6 shared input rows cover all 4 output rows' 3-tap kh windows.
            float pa[6];
            #pragma unroll
            for (int r = 0; r < 6; ++r)
                pa[r] = lx[c * CHW + r * LDS_W + col + kw];
            #pragma unroll
            for (int kh = 0; kh < 3; ++kh) {
                int t = (cc * 3 + kh) * 3 + kw;      // local tap 0..71
                float4 q = ltPM[tb0 + t];            // dual-addr b128, bank-disjoint
                f32x2  D = ltD [tb0 + t];
                f32x2  P = {q.x, q.y}, M = {q.z, q.w};
                #pragma unroll
                for (int r = 0; r < 4; ++r) {
                    f32x2 pv = {pa[r + kh], pa[r + kh]};
                    a[r] = __builtin_elementwise_fma(M, pv, a[r]);
                    h[r] = __builtin_elementwise_fma(
                        D, __builtin_elementwise_max(pv - P, zz), h[r]);
                }
            }
        }
    }

    // ---- Epilogue: cs-combine via shfl across half-waves, lanes<32 store. -
    int o0 = 4 * g + 2 * pgrp;
    int HW = H_ * W_;
    #pragma unroll
    for (int r = 0; r < 4; ++r) {
        f32x2 s = a[r] + h[r] + bb;              // bb halves sum to full SumB0
        s.x += __shfl_xor(s.x, 32);
        s.y += __shfl_xor(s.y, 32);
        if (cs == 0) {
            int ob = ((b * OUT_CH + o0) * H_ + (ho0 + r)) * W_ + col;
            out[ob     ] = s.x;
            out[ob + HW] = s.y;
        }
    }
}

extern "C" void kernel_launch(void* const* d_in, const int* in_sizes, int n_in,
                              void* d_out, int out_size, void* d_ws, size_t ws_size,
                              hipStream_t stream) {
    const float* x   = (const float*)d_in[0];
    const float* pos = (const float*)d_in[1];
    const float* val = (const float*)d_in[2];

    dim3 grid(64, 8);
    apc_fused<<<grid, 128, 0, stream>>>(x, pos, val, (float*)d_out);
}

// Round 10
// 66.934 us; speedup vs baseline: 1.5255x; 1.1127x over previous
//
#include <hip/hip_runtime.h>

#define IN_CH 16
#define OUT_CH 32
#define NUM_INPUTS 144   // IN_CH * 3 * 3
#define H_ 32
#define W_ 32
#define TILE_H 4
#define LDS_H 6          // TILE_H + 2 halo
#define LDS_W 34         // 34 mod 32 == 2 -> exactly 2 lanes/bank (free)
#define CHW (LDS_H * LDS_W)   // 204

typedef __attribute__((ext_vector_type(2))) float f32x2;

// ---------------------------------------------------------------------------
// FINAL (R7 structure — best measured: 66.8us total, kernel ~7us vs ~6.7us
// LDS-pipe floor; R8's 4-row variant spilled at VGPR=256, R9's capped
// version lost TLP at 4 waves/CU — both regressed).
//
// One fused kernel. Grid (64 spatial, 8 quads) = 512 blocks = 2/CU; block
// 256 thr = 4 waves -> 8 waves/CU = 2/SIMD (R6 lesson: 1 wave/SIMD cannot
// hide ds_read latency). Thread = 2 rows x 2 ch x 8 input chans (2-way
// c-split IN-block, partials combined via 2KB LDS reduction -> no atomics,
// no memset, no workspace, no separate prep kernel).
//
// Phase 0a: stage 16ch x 6x34 zero-padded x tile (13 KB).
// Phase 0b: thr 0..143 build tap tables: y(p)=m0*p+b0+(m1-m0)*max(p-p1,0)
//   (continuous at p1 -> exact clipped-tail reproduction), split arrays:
//   ltPM[pair][tap] = (p1,p1',m0,m0') b128; ltD = (dm,dm') b64; ltB b64.
// Phase 1: per wave (fixed pair,cs): bb = sum of b0 over its 72 taps ONCE
//   (lane-parallel LDS + shfl_xor butterfly), then 72-tap unrolled loop:
//   1 b128 + 1 b64 broadcast + 4 patch b32 per (c,kw) group. All LDS.
// Epilogue: cs1 writes 4 partials to lred; cs0 adds and stores.
// ---------------------------------------------------------------------------
__global__ __launch_bounds__(256, 2) void apc_fused(
        const float* __restrict__ x,
        const float* __restrict__ pos,
        const float* __restrict__ val,
        float* __restrict__ out) {
    __shared__ float  lx[IN_CH * CHW];        // 13056 B
    __shared__ float4 ltPM[2 * NUM_INPUTS];   //  4608 B
    __shared__ f32x2  ltD [2 * NUM_INPUTS];   //  2304 B
    __shared__ f32x2  ltB [2 * NUM_INPUTS];   //  2304 B
    __shared__ float4 lred[128];              //  2048 B   (total 24.3 KB)

    int bx  = blockIdx.x;            // 0..63: b*8 + row_tile
    int b   = bx >> 3;
    int ho0 = (bx & 7) * TILE_H;
    int g   = blockIdx.y;            // channel-quad: o = 4g..4g+3
    int tid = threadIdx.x;

    // ---- Phase 0a: stage x tile with zero-padded halo. --------------------
    for (int idx = tid; idx < IN_CH * CHW; idx += 256) {
        int c   = idx / CHW;
        int rem = idx - c * CHW;
        int r   = rem / LDS_W;
        int col = rem - r * LDS_W;
        int gr  = ho0 + r - 1;
        int gc  = col - 1;
        float v = 0.f;
        if ((unsigned)gr < (unsigned)H_ && (unsigned)gc < (unsigned)W_)
            v = x[((b * IN_CH + c) * H_ + gr) * W_ + gc];
        lx[idx] = v;
    }

    // ---- Phase 0b: build table slice (threads 0..143, one tap each). ------
    if (tid < NUM_INPUTS) {
        // pos/val[(i,o,p)]: 4-channel slice = 12 floats at i*96 + g*12,
        // byte offset 384i+48g -> 16B-aligned float4s.
        const float4* pp = (const float4*)(pos + tid * 96 + g * 12);
        const float4* vv = (const float4*)(val + tid * 96 + g * 12);
        float4 pA = pp[0], pB = pp[1], pC = pp[2];
        float4 vA = vv[0], vB = vv[1], vC = vv[2];
        float P[12] = {pA.x,pA.y,pA.z,pA.w, pB.x,pB.y,pB.z,pB.w, pC.x,pC.y,pC.z,pC.w};
        float V[12] = {vA.x,vA.y,vA.z,vA.w, vB.x,vB.y,vB.z,vB.w, vC.x,vC.y,vC.z,vC.w};
        float p1[4], m0[4], dm[4], b0[4];
        #pragma unroll
        for (int k = 0; k < 4; ++k) {
            float q0 = P[3*k], q1 = P[3*k+1], q2 = P[3*k+2];
            float w0 = V[3*k], w1 = V[3*k+1], w2 = V[3*k+2];
            float s0 = (w1 - w0) / (q1 - q0);
            float s1 = (w2 - w1) / (q2 - q1);
            p1[k] = q1; m0[k] = s0; dm[k] = s1 - s0; b0[k] = w0 - s0 * q0;
        }
        ltPM[tid]              = make_float4(p1[0], p1[1], m0[0], m0[1]);
        ltD [tid]              = (f32x2){dm[0], dm[1]};
        ltB [tid]              = (f32x2){b0[0], b0[1]};
        ltPM[NUM_INPUTS + tid] = make_float4(p1[2], p1[3], m0[2], m0[3]);
        ltD [NUM_INPUTS + tid] = (f32x2){dm[2], dm[3]};
        ltB [NUM_INPUTS + tid] = (f32x2){b0[2], b0[3]};
    }
    __syncthreads();

    int col  = tid & 31;             // output col
    int trow = (tid >> 5) & 1;       // -> local output rows 2*trow, 2*trow+1
    int pgrp = (tid >> 6) & 1;       // channel pair within quad (wave-uniform)
    int cs   = tid >> 7;             // input-channel half (wave-uniform)
    int i0   = cs * 72;              // first tap of this half
    int tb0  = pgrp * NUM_INPUTS + i0;
    int base = (2 * trow) * LDS_W + col;
    int lane = tid & 63;

    // bb = sum of b0 over this (pgrp,cs) half's 72 taps, once per wave:
    // lane-parallel LDS reads (8B stride -> 2 lanes/bank, free) + butterfly.
    f32x2 bb = ltB[tb0 + lane];
    if (lane < 8) bb += ltB[tb0 + 64 + lane];
    #pragma unroll
    for (int m = 1; m < 64; m <<= 1) {
        bb.x += __shfl_xor(bb.x, m);
        bb.y += __shfl_xor(bb.y, m);
    }

    f32x2 aA = {0,0}, hA = {0,0};    // local row 2*trow
    f32x2 aB = {0,0}, hB = {0,0};    // local row 2*trow+1
    const f32x2 zz = {0.f, 0.f};

    #pragma unroll
    for (int cc = 0; cc < 8; ++cc) {
        int c = cs * 8 + cc;         // global input channel
        #pragma unroll
        for (int kw = 0; kw < 3; ++kw) {
            // 4 shared input rows cover both output rows' 3-tap kh windows.
            float p0 = lx[c * CHW + base + 0 * LDS_W + kw];
            float p1 = lx[c * CHW + base + 1 * LDS_W + kw];
            float p2 = lx[c * CHW + base + 2 * LDS_W + kw];
            float p3 = lx[c * CHW + base + 3 * LDS_W + kw];
            float pa[4] = {p0, p1, p2, p3};
            #pragma unroll
            for (int kh = 0; kh < 3; ++kh) {
                int ti = pgrp * NUM_INPUTS + (c * 3 + kh) * 3 + kw;
                float4 q = ltPM[ti];               // broadcast b128
                f32x2  D = ltD[ti];                // broadcast b64
                f32x2  P = {q.x, q.y}, M = {q.z, q.w};
                f32x2 qA = {pa[kh],     pa[kh]};
                f32x2 qB = {pa[kh + 1], pa[kh + 1]};
                aA = __builtin_elementwise_fma(M, qA, aA);
                hA = __builtin_elementwise_fma(D, __builtin_elementwise_max(qA - P, zz), hA);
                aB = __builtin_elementwise_fma(M, qB, aB);
                hB = __builtin_elementwise_fma(D, __builtin_elementwise_max(qB - P, zz), hB);
            }
        }
    }

    f32x2 rA = aA + hA + bb;         // bb: this half's Sum(b0), once per output
    f32x2 rB = aB + hB + bb;

    // ---- c-split combine: cs1 -> LDS, cs0 adds and stores. ----------------
    if (cs == 1)
        lred[tid - 128] = make_float4(rA.x, rA.y, rB.x, rB.y);
    __syncthreads();
    if (cs == 0) {
        float4 q = lred[tid];        // partner thread tid+128, same (col,trow,pgrp)
        rA.x += q.x; rA.y += q.y; rB.x += q.z; rB.y += q.w;
        int hoA = ho0 + 2 * trow;
        int o0  = 4 * g + 2 * pgrp;
        int HW  = H_ * W_;
        int ob  = ((b * OUT_CH + o0) * H_ + hoA) * W_ + col;
        out[ob          ] = rA.x;
        out[ob +      HW] = rA.y;
        out[ob + W_     ] = rB.x;
        out[ob + W_ + HW] = rB.y;
    }
}

extern "C" void kernel_launch(void* const* d_in, const int* in_sizes, int n_in,
                              void* d_out, int out_size, void* d_ws, size_t ws_size,
                              hipStream_t stream) {
    const float* x   = (const float*)d_in[0];
    const float* pos = (const float*)d_in[1];
    const float* val = (const float*)d_in[2];

    dim3 grid(64, 8);
    apc_fused<<<grid, 256, 0, stream>>>(x, pos, val, (float*)d_out);
}